// Round 1
// baseline (3364.469 us; speedup 1.0000x reference)
//
#include <hip/hip_runtime.h>
#include <hip/hip_bf16.h>

#define NTOK 49
#define CDIM 128
#define NH 4
#define HD 32

// LDS layout (dword offsets into one shared float array)
#define OFF_Q 0            // fp32 [4][49*33]: h*1617 + n*33 + d   (bank (n+d)%32: conflict-free)
#define OFF_K 6468         // fp32 [4][49*33]
#define OFF_V 12936        // bf16 [4][49*34] as u16: h*1666 + n*34 + d (even stride -> 4B-aligned pairs)
#define OFF_UB 16268       // fp32 [49] relu(u_bias)
#define SMEM_DW 16317      // 65268 bytes < 64 KiB
// overlays (regions dead by the time these are written):
#define OFF_ATTN OFF_Q     // fp32 [49][132] gated attention output (n*132 + c)
#define OFF_FIN  OFF_K     // fp32 [49][132] final projected output

__global__ __launch_bounds__(256)
void fused_win_attn(const float* __restrict__ x,
                    const float* __restrict__ u_temp,
                    const float* __restrict__ u_bias,
                    const float* __restrict__ gate,
                    const float* __restrict__ qkv_w,
                    const float* __restrict__ qkv_b,
                    const float* __restrict__ proj_w,
                    const float* __restrict__ proj_b,
                    const float* __restrict__ rel_table,
                    const int*   __restrict__ rel_index,
                    float* __restrict__ out)
{
    __shared__ float smem[SMEM_DW];
    const int b   = blockIdx.x;
    const int tid = threadIdx.x;
    const int n   = tid & 63;                                   // lane = token row
    const int wv  = __builtin_amdgcn_readfirstlane(tid >> 6);   // wave id, forced SGPR-uniform
    const int nc  = (n < NTOK) ? n : (NTOK - 1);
    const bool act = (n < NTOK);

    // ---- phase 0: per-token scalars ----
    if (tid < NTOK) {
        float ub = u_bias[(size_t)b * NTOK + tid];
        smem[OFF_UB + tid] = ub > 0.f ? ub : 0.f;
    }
    float rT;
    {
        float u  = u_temp[(size_t)b * NTOK + nc];
        float sg = 1.f / (1.f + __expf(-u));
        rT = 1.f / (0.1f + 4.0f * sg);
    }

    // ---- x row -> registers (loaded exactly once per lane) ----
    float xr[CDIM];
    {
        const float* xrow = x + (size_t)(b * NTOK + nc) * CDIM;
        #pragma unroll
        for (int i = 0; i < CDIM / 4; ++i) {
            float4 t = reinterpret_cast<const float4*>(xrow)[i];
            xr[4*i+0] = t.x; xr[4*i+1] = t.y; xr[4*i+2] = t.z; xr[4*i+3] = t.w;
        }
    }

    // ---- phase 1: QKV GEMM. wave wv owns output cols j in [wv*96, wv*96+96).
    // Weight addresses are wave-uniform -> scalar loads; x is per-lane VGPR. ----
    __hip_bfloat16* svb = reinterpret_cast<__hip_bfloat16*>(smem + OFF_V);
    #pragma unroll 1
    for (int jb = 0; jb < 12; ++jb) {
        const int jbase = wv * 96 + jb * 8;
        float acc[8];
        #pragma unroll
        for (int i = 0; i < 8; ++i) acc[i] = qkv_b[jbase + i];
        #pragma unroll
        for (int c = 0; c < CDIM; ++c) {
            #pragma unroll
            for (int i = 0; i < 8; ++i)
                acc[i] = fmaf(xr[c], qkv_w[(size_t)(jbase + i) * CDIM + c], acc[i]);
        }
        if (act) {
            #pragma unroll
            for (int i = 0; i < 8; ++i) {
                const int j = jbase + i;
                const int s = j >> 7, h = (j >> 5) & 3, d = j & 31;
                if (s == 0)      smem[OFF_Q + h*1617 + n*33 + d] = acc[i] * rT;  // q/T
                else if (s == 1) smem[OFF_K + h*1617 + n*33 + d] = acc[i];
                else             svb[h*1666 + n*34 + d] = __float2bfloat16(acc[i]);
            }
        }
    }
    __syncthreads();

    // ---- phase 2: attention, head h = wv, query row nc ----
    float qr[HD];
    #pragma unroll
    for (int d = 0; d < HD; ++d)
        qr[d] = smem[OFF_Q + wv*1617 + nc*33 + d];
    __syncthreads();   // all q reads done; q region may now be overwritten by sattn

    float sc[NTOK];
    #pragma unroll
    for (int m = 0; m < NTOK; ++m) {
        float dot = 0.f;
        #pragma unroll
        for (int d = 0; d < HD; ++d)
            dot = fmaf(qr[d], smem[OFF_K + wv*1617 + m*33 + d], dot);   // broadcast read
        const int ridx = rel_index[nc * NTOK + m];
        const float bias = rel_table[ridx * NH + wv];
        sc[m] = dot * 0.17677669529663687f + bias - smem[OFF_UB + m];
    }
    // softmax over m (register-resident)
    float mx = sc[0];
    #pragma unroll
    for (int m = 1; m < NTOK; ++m) mx = fmaxf(mx, sc[m]);
    float sum = 0.f;
    #pragma unroll
    for (int m = 0; m < NTOK; ++m) { sc[m] = __expf(sc[m] - mx); sum += sc[m]; }
    const float rs = 1.f / sum;

    // PV: oa[d] = sum_m p_m * v[h][m][d]  (v is bf16 pairs, broadcast reads)
    float oa[HD];
    #pragma unroll
    for (int d = 0; d < HD; ++d) oa[d] = 0.f;
    #pragma unroll
    for (int m = 0; m < NTOK; ++m) {
        const float p = sc[m] * rs;
        const unsigned int* vrow =
            reinterpret_cast<const unsigned int*>(svb + wv*1666 + m*34);
        #pragma unroll
        for (int d2 = 0; d2 < HD / 2; ++d2) {
            const unsigned int vv = vrow[d2];
            const float v0 = __uint_as_float(vv << 16);
            const float v1 = __uint_as_float(vv & 0xffff0000u);
            oa[2*d2]   = fmaf(p, v0, oa[2*d2]);
            oa[2*d2+1] = fmaf(p, v1, oa[2*d2+1]);
        }
    }
    const float g = gate[(size_t)b * NH * NTOK + wv * NTOK + nc];
    if (act) {
        #pragma unroll
        for (int d = 0; d < HD; ++d)
            smem[OFF_ATTN + n*132 + wv*HD + d] = oa[d] * g;
    }
    __syncthreads();

    // ---- phase 3: output projection. wave wv owns cols e in [wv*32, wv*32+32). ----
    float ar[CDIM];
    #pragma unroll
    for (int c = 0; c < CDIM; ++c)
        ar[c] = smem[OFF_ATTN + nc*132 + c];
    #pragma unroll 1
    for (int eb = 0; eb < 4; ++eb) {
        const int ebase = wv * 32 + eb * 8;
        float acc[8];
        #pragma unroll
        for (int i = 0; i < 8; ++i) acc[i] = proj_b[ebase + i];
        #pragma unroll
        for (int c = 0; c < CDIM; ++c) {
            #pragma unroll
            for (int i = 0; i < 8; ++i)
                acc[i] = fmaf(ar[c], proj_w[(size_t)(ebase + i) * CDIM + c], acc[i]);
        }
        if (act) {
            #pragma unroll
            for (int i = 0; i < 8; ++i)
                smem[OFF_FIN + n*132 + ebase + i] = acc[i];
        }
    }
    __syncthreads();

    // ---- coalesced copy-out ----
    float* orow = out + (size_t)b * (NTOK * CDIM);
    for (int base = tid * 4; base < NTOK * CDIM; base += 1024) {
        const int rr = base >> 7, c = base & 127;
        float4 t;
        t.x = smem[OFF_FIN + rr*132 + c + 0];
        t.y = smem[OFF_FIN + rr*132 + c + 1];
        t.z = smem[OFF_FIN + rr*132 + c + 2];
        t.w = smem[OFF_FIN + rr*132 + c + 3];
        reinterpret_cast<float4*>(orow)[base >> 2] = t;
    }
}

extern "C" void kernel_launch(void* const* d_in, const int* in_sizes, int n_in,
                              void* d_out, int out_size, void* d_ws, size_t ws_size,
                              hipStream_t stream) {
    const float* x  = (const float*)d_in[0];
    const float* ut = (const float*)d_in[1];
    const float* ub = (const float*)d_in[2];
    const float* tg = (const float*)d_in[3];
    const float* qw = (const float*)d_in[4];
    const float* qb = (const float*)d_in[5];
    const float* pw = (const float*)d_in[6];
    const float* pb = (const float*)d_in[7];
    const float* rt = (const float*)d_in[8];
    const int*   ri = (const int*)d_in[9];
    float* o = (float*)d_out;
    const int B = in_sizes[0] / (NTOK * CDIM);
    fused_win_attn<<<B, 256, 0, stream>>>(x, ut, ub, tg, qw, qb, pw, pb, rt, ri, o);
}

// Round 2
// 508.180 us; speedup vs baseline: 6.6206x; 6.6206x over previous
//
#include <hip/hip_runtime.h>

typedef short s8v __attribute__((ext_vector_type(8)));
typedef float f4v __attribute__((ext_vector_type(4)));

#define NTOK 49
// LDS float offsets
#define LDS_Q    0        // fp32 [49][132]  q (pre-scaled); later: P (bf16, overlay); later: attn_out fp32
#define LDS_K    6468     // fp32 [49][132]  k; later: v fp32 (overlay)
#define LDS_RT   12936    // [49] 0.17678/T
#define LDS_UB   12985    // [49] relu(u_bias)
#define LDS_GATE 13034    // [4][49]
#define LDS_TOT  13230    // 52920 bytes

// ws byte layout: qkv_hi u16[49152] @0 ; qkv_lo @98304 ; proj_hi u16[16384] @196608 ;
//                 proj_lo @229376 ; bias f32[4][49][49] @262144 ; total 300560 B
#define WS_BIAS_OFF 262144

__device__ __forceinline__ unsigned short f2bf(float f){
    unsigned x = __float_as_uint(f);
    x += 0x7fffu + ((x >> 16) & 1u);
    return (unsigned short)(x >> 16);
}
__device__ __forceinline__ float bf2f(unsigned short h){
    return __uint_as_float(((unsigned)h) << 16);
}
__device__ __forceinline__ void split8(const float* f, s8v& hi, s8v& lo){
    #pragma unroll
    for (int j = 0; j < 8; ++j){
        unsigned short h = f2bf(f[j]);
        hi[j] = (short)h;
        lo[j] = (short)f2bf(f[j] - bf2f(h));
    }
}

__global__ void prep_kernel(const float* __restrict__ qkv_w, const float* __restrict__ proj_w,
                            const float* __restrict__ rel_table, const int* __restrict__ rel_index,
                            void* __restrict__ ws){
    int i = blockIdx.x * 256 + threadIdx.x;
    unsigned short* qh = (unsigned short*)ws;
    unsigned short* ql = qh + 49152;
    unsigned short* ph = (unsigned short*)((char*)ws + 196608);
    unsigned short* pl = (unsigned short*)((char*)ws + 229376);
    float* biasT = (float*)((char*)ws + WS_BIAS_OFF);
    if (i < 49152){
        float v = qkv_w[i];
        unsigned short h = f2bf(v);
        qh[i] = h; ql[i] = f2bf(v - bf2f(h));
    } else if (i < 65536){
        int j = i - 49152;
        float v = proj_w[j];
        unsigned short h = f2bf(v);
        ph[j] = h; pl[j] = f2bf(v - bf2f(h));
    } else if (i < 75140){
        int j = i - 65536;
        int h = j / 2401, r = j % 2401;       // r = q*49 + k
        biasT[h*2401 + r] = rel_table[rel_index[r]*4 + h];
    }
}

#define MFMA(a,b,c) __builtin_amdgcn_mfma_f32_16x16x32_bf16((a),(b),(c),0,0,0)

__global__ __launch_bounds__(256, 2)
void win_attn(const float* __restrict__ x, const float* __restrict__ u_temp,
              const float* __restrict__ u_bias, const float* __restrict__ gate,
              const float* __restrict__ qkv_b, const float* __restrict__ proj_b,
              const void* __restrict__ ws, float* __restrict__ out)
{
    __shared__ float sm[LDS_TOT];
    const int b = blockIdx.x, tid = threadIdx.x;
    const int l  = tid & 63;
    const int w  = __builtin_amdgcn_readfirstlane(tid >> 6);   // wave = head
    const int lc = l & 15, q4 = l >> 4;

    // ---- stage per-window scalars ----
    if (tid < NTOK){
        float u  = u_temp[b*NTOK + tid];
        float sg = 1.f / (1.f + __expf(-u));
        sm[LDS_RT + tid] = 0.17677669529663687f / (0.1f + 4.f*sg);   // (1/sqrt32)/T
        float ub = u_bias[b*NTOK + tid];
        sm[LDS_UB + tid] = ub > 0.f ? ub : 0.f;
    }
    if (tid < 196) sm[LDS_GATE + tid] = gate[b*196 + tid];
    __syncthreads();

    const unsigned short* qkh = (const unsigned short*)ws;
    const unsigned short* qkl = qkh + 49152;

    // ---- phase A: QKV GEMM (split-bf16, 3 MFMAs). wave w n-tiles: {2w,2w+1, 8+2w,9+2w, 16+2w,17+2w} ----
    f4v vhold[2][4];   // v D-tiles [t][mt] held in regs until after barrier 3
    #pragma unroll
    for (int mp = 0; mp < 2; ++mp){
        s8v ah[2][4], al[2][4];
        #pragma unroll
        for (int m2 = 0; m2 < 2; ++m2){
            int row = (mp*2 + m2)*16 + lc; if (row > 48) row = 48;
            const float* xp = x + ((size_t)b*NTOK + row)*128 + q4*8;
            #pragma unroll
            for (int kf = 0; kf < 4; ++kf){
                float xv[8];
                float4 t0 = *(const float4*)(xp + kf*32);
                float4 t1 = *(const float4*)(xp + kf*32 + 4);
                xv[0]=t0.x; xv[1]=t0.y; xv[2]=t0.z; xv[3]=t0.w;
                xv[4]=t1.x; xv[5]=t1.y; xv[6]=t1.z; xv[7]=t1.w;
                split8(xv, ah[m2][kf], al[m2][kf]);
            }
        }
        #pragma unroll
        for (int g = 0; g < 3; ++g){
            #pragma unroll
            for (int t = 0; t < 2; ++t){
                int nt  = (g==0 ? 2*w : (g==1 ? 8+2*w : 16+2*w)) + t;
                int col = nt*16 + lc;
                s8v bh[4], bl[4];
                #pragma unroll
                for (int kf = 0; kf < 4; ++kf){
                    int off = col*128 + kf*32 + q4*8;
                    bh[kf] = *(const s8v*)(qkh + off);
                    bl[kf] = *(const s8v*)(qkl + off);
                }
                float bia = qkv_b[col];
                #pragma unroll
                for (int m2 = 0; m2 < 2; ++m2){
                    f4v acc = {bia, bia, bia, bia};
                    #pragma unroll
                    for (int kf = 0; kf < 4; ++kf){
                        acc = MFMA(ah[m2][kf], bh[kf], acc);
                        acc = MFMA(ah[m2][kf], bl[kf], acc);
                        acc = MFMA(al[m2][kf], bh[kf], acc);
                    }
                    int mt = mp*2 + m2;
                    if (g == 2){
                        vhold[t][mt] = acc;
                    } else {
                        #pragma unroll
                        for (int r = 0; r < 4; ++r){
                            int row = mt*16 + q4*4 + r;
                            if (row < NTOK){
                                if (g == 0) sm[LDS_Q + row*132 + col] = acc[r] * sm[LDS_RT + row];
                                else        sm[LDS_K + row*132 + (col - 128)] = acc[r];
                            }
                        }
                    }
                }
            }
        }
    }
    __syncthreads();   // #2: q,k complete

    // ---- phase B: S^T = K·Q^T per head (wave = head) ----
    s8v Kh[4], Kl[4], Qh[4], Ql[4];
    #pragma unroll
    for (int t = 0; t < 4; ++t){
        int row = 16*t + lc; if (row > 48) row = 48;
        float fv[8];
        {
            const float* p = &sm[LDS_K + row*132 + w*32 + q4*8];
            float4 a0 = *(const float4*)p; float4 a1 = *(const float4*)(p + 4);
            fv[0]=a0.x; fv[1]=a0.y; fv[2]=a0.z; fv[3]=a0.w;
            fv[4]=a1.x; fv[5]=a1.y; fv[6]=a1.z; fv[7]=a1.w;
            split8(fv, Kh[t], Kl[t]);
        }
        {
            const float* p = &sm[LDS_Q + row*132 + w*32 + q4*8];
            float4 a0 = *(const float4*)p; float4 a1 = *(const float4*)(p + 4);
            fv[0]=a0.x; fv[1]=a0.y; fv[2]=a0.z; fv[3]=a0.w;
            fv[4]=a1.x; fv[5]=a1.y; fv[6]=a1.z; fv[7]=a1.w;
            split8(fv, Qh[t], Ql[t]);
        }
    }
    const float* biasT = (const float*)((const char*)ws + WS_BIAS_OFF);
    f4v S[4][4];   // S^T tiles: row=key, col=query
    #pragma unroll
    for (int mt = 0; mt < 4; ++mt){
        #pragma unroll
        for (int nt = 0; nt < 4; ++nt){
            int qy = nt*16 + lc; if (qy > 48) qy = 48;
            f4v a;
            #pragma unroll
            for (int r = 0; r < 4; ++r){
                int ky = mt*16 + q4*4 + r; if (ky > 48) ky = 48;
                a[r] = biasT[w*2401 + qy*49 + ky] - sm[LDS_UB + ky];
            }
            a = MFMA(Kh[mt], Qh[nt], a);
            a = MFMA(Kh[mt], Ql[nt], a);
            a = MFMA(Kl[mt], Qh[nt], a);
            S[mt][nt] = a;
        }
    }
    // mask pad keys (only mt==3 can exceed)
    #pragma unroll
    for (int r = 0; r < 4; ++r){
        int ky = 48 + q4*4 + r;
        if (ky >= NTOK){
            S[3][0][r] = -1e30f; S[3][1][r] = -1e30f; S[3][2][r] = -1e30f; S[3][3][r] = -1e30f;
        }
    }
    // softmax per query (column): 16 in-lane + cross-quad shuffles
    #pragma unroll
    for (int nt = 0; nt < 4; ++nt){
        float mx = -3e38f;
        #pragma unroll
        for (int mt = 0; mt < 4; ++mt)
            #pragma unroll
            for (int r = 0; r < 4; ++r) mx = fmaxf(mx, S[mt][nt][r]);
        mx = fmaxf(mx, __shfl_xor(mx, 16));
        mx = fmaxf(mx, __shfl_xor(mx, 32));
        float sum = 0.f;
        #pragma unroll
        for (int mt = 0; mt < 4; ++mt)
            #pragma unroll
            for (int r = 0; r < 4; ++r){
                float e = __expf(S[mt][nt][r] - mx);
                S[mt][nt][r] = e; sum += e;
            }
        sum += __shfl_xor(sum, 16);
        sum += __shfl_xor(sum, 32);
        float rs = 1.f / sum;
        #pragma unroll
        for (int mt = 0; mt < 4; ++mt)
            #pragma unroll
            for (int r = 0; r < 4; ++r) S[mt][nt][r] *= rs;
    }
    __syncthreads();   // #3: all waves done reading q,k slots

    // ---- write P (bf16, q-slot, XOR-swizzled chunks) and v (fp32, k-slot) ----
    unsigned short* P = (unsigned short*)sm;
    #pragma unroll
    for (int nt = 0; nt < 4; ++nt){
        int qy = nt*16 + lc;
        if (qy < NTOK){
            #pragma unroll
            for (int mt = 0; mt < 4; ++mt)
                #pragma unroll
                for (int r = 0; r < 4; ++r){
                    int ky = mt*16 + q4*4 + r;
                    P[w*3136 + qy*64 + (((ky>>3) ^ (qy&7)) << 3) + (ky&7)] = f2bf(S[mt][nt][r]);
                }
        }
    }
    #pragma unroll
    for (int t = 0; t < 2; ++t)
        #pragma unroll
        for (int mt = 0; mt < 4; ++mt)
            #pragma unroll
            for (int r = 0; r < 4; ++r){
                int row = mt*16 + q4*4 + r;
                if (row < NTOK) sm[LDS_K + row*132 + w*32 + t*16 + lc] = vhold[t][mt][r];
            }

    // ---- PV (same-wave LDS round trip, no barrier needed) ----
    s8v Pa[4][2];
    #pragma unroll
    for (int mt = 0; mt < 4; ++mt)
        #pragma unroll
        for (int kf = 0; kf < 2; ++kf){
            int qy = mt*16 + lc; if (qy > 48) qy = 48;
            int ch = (4*kf + q4) ^ (qy & 7);
            Pa[mt][kf] = *(const s8v*)(P + w*3136 + qy*64 + ch*8);
        }
    s8v Vb[2][2];
    #pragma unroll
    for (int t = 0; t < 2; ++t)
        #pragma unroll
        for (int kf = 0; kf < 2; ++kf){
            #pragma unroll
            for (int j = 0; j < 8; ++j){
                int key = kf*32 + q4*8 + j; if (key > 48) key = 48;
                Vb[t][kf][j] = (short)f2bf(sm[LDS_K + key*132 + w*32 + t*16 + lc]);
            }
        }
    f4v O[4][2];
    #pragma unroll
    for (int mt = 0; mt < 4; ++mt)
        #pragma unroll
        for (int t = 0; t < 2; ++t){
            f4v o = {0.f, 0.f, 0.f, 0.f};
            o = MFMA(Pa[mt][0], Vb[t][0], o);
            o = MFMA(Pa[mt][1], Vb[t][1], o);
            O[mt][t] = o;
        }
    __syncthreads();   // #4: all P/v reads done; q-slot reusable

    // ---- gate + stage attn_out (fp32, q-slot) ----
    #pragma unroll
    for (int mt = 0; mt < 4; ++mt)
        #pragma unroll
        for (int t = 0; t < 2; ++t)
            #pragma unroll
            for (int r = 0; r < 4; ++r){
                int row = mt*16 + q4*4 + r;
                if (row < NTOK)
                    sm[LDS_Q + row*132 + w*32 + t*16 + lc] = O[mt][t][r] * sm[LDS_GATE + w*49 + row];
            }
    __syncthreads();   // #5: attn_out complete

    // ---- proj GEMM (split-bf16, 3 MFMAs). wave w n-tiles {2w, 2w+1} ----
    const unsigned short* ph = (const unsigned short*)((const char*)ws + 196608);
    const unsigned short* pl = (const unsigned short*)((const char*)ws + 229376);
    s8v Bh[2][4], Bl[2][4];
    #pragma unroll
    for (int t = 0; t < 2; ++t){
        int col = (2*w + t)*16 + lc;
        #pragma unroll
        for (int kf = 0; kf < 4; ++kf){
            int off = col*128 + kf*32 + q4*8;
            Bh[t][kf] = *(const s8v*)(ph + off);
            Bl[t][kf] = *(const s8v*)(pl + off);
        }
    }
    #pragma unroll
    for (int mt = 0; mt < 4; ++mt){
        int row = mt*16 + lc; if (row > 48) row = 48;
        s8v Ah[4], Al[4];
        #pragma unroll
        for (int kf = 0; kf < 4; ++kf){
            float fv[8];
            const float* p = &sm[LDS_Q + row*132 + kf*32 + q4*8];
            float4 a0 = *(const float4*)p; float4 a1 = *(const float4*)(p + 4);
            fv[0]=a0.x; fv[1]=a0.y; fv[2]=a0.z; fv[3]=a0.w;
            fv[4]=a1.x; fv[5]=a1.y; fv[6]=a1.z; fv[7]=a1.w;
            split8(fv, Ah[kf], Al[kf]);
        }
        #pragma unroll
        for (int t = 0; t < 2; ++t){
            int col = (2*w + t)*16 + lc;
            float bia = proj_b[col];
            f4v acc = {bia, bia, bia, bia};
            #pragma unroll
            for (int kf = 0; kf < 4; ++kf){
                acc = MFMA(Ah[kf], Bh[t][kf], acc);
                acc = MFMA(Ah[kf], Bl[t][kf], acc);
                acc = MFMA(Al[kf], Bh[t][kf], acc);
            }
            #pragma unroll
            for (int r = 0; r < 4; ++r){
                int r2 = mt*16 + q4*4 + r;
                if (r2 < NTOK) out[((size_t)b*NTOK + r2)*128 + col] = acc[r];
            }
        }
    }
}

extern "C" void kernel_launch(void* const* d_in, const int* in_sizes, int n_in,
                              void* d_out, int out_size, void* d_ws, size_t ws_size,
                              hipStream_t stream) {
    const float* x  = (const float*)d_in[0];
    const float* ut = (const float*)d_in[1];
    const float* ub = (const float*)d_in[2];
    const float* tg = (const float*)d_in[3];
    const float* qw = (const float*)d_in[4];
    const float* qb = (const float*)d_in[5];
    const float* pw = (const float*)d_in[6];
    const float* pb = (const float*)d_in[7];
    const float* rt = (const float*)d_in[8];
    const int*   ri = (const int*)d_in[9];
    float* o = (float*)d_out;
    const int B = in_sizes[0] / (NTOK * 128);

    prep_kernel<<<294, 256, 0, stream>>>(qw, pw, rt, ri, d_ws);
    win_attn<<<B, 256, 0, stream>>>(x, ut, ub, tg, qb, pb, d_ws, o);
}

// Round 3
// 457.702 us; speedup vs baseline: 7.3508x; 1.1103x over previous
//
#include <hip/hip_runtime.h>

typedef short s8v __attribute__((ext_vector_type(8)));
typedef float f4v __attribute__((ext_vector_type(4)));

#define NTOK 49
// LDS float offsets
#define LDS_Q    0        // fp32 [49][132] q; later P (bf16 swizzled); later attn_hi/lo (u16 swizzled)
#define LDS_K    6468     // fp32 [49][132] k; later v fp32 (overlay)
#define LDS_RT   12936    // [49] 0.17678/T
#define LDS_UB   12985    // [49] relu(u_bias)
#define LDS_GATE 13034    // [4][49]
#define LDS_TOT  13230    // 52920 bytes -> 53248 granule; 3 blocks/CU

// ws byte layout: qkv_hi u16[49152] @0 ; qkv_lo @98304 ; proj_hi u16[16384] @196608 ;
//                 proj_lo @229376 ; bias f32[4][49][49] @262144
#define WS_BIAS_OFF 262144

__device__ __forceinline__ unsigned short f2bf(float f){          // RNE (used sparingly)
    unsigned x = __float_as_uint(f);
    x += 0x7fffu + ((x >> 16) & 1u);
    return (unsigned short)(x >> 16);
}
__device__ __forceinline__ float bf2f(unsigned short h){
    return __uint_as_float(((unsigned)h) << 16);
}
// cheap truncation split: hi = top16(f), lo = top16(f - hi). err <= 2^-16 |f|
__device__ __forceinline__ void split8t(const float* f, s8v& hi, s8v& lo){
    #pragma unroll
    for (int j = 0; j < 8; ++j){
        unsigned u = __float_as_uint(f[j]);
        hi[j] = (short)(u >> 16);
        float r = f[j] - __uint_as_float(u & 0xffff0000u);
        lo[j] = (short)(__float_as_uint(r) >> 16);
    }
}

__global__ void prep_kernel(const float* __restrict__ qkv_w, const float* __restrict__ proj_w,
                            const float* __restrict__ rel_table, const int* __restrict__ rel_index,
                            void* __restrict__ ws){
    int i = blockIdx.x * 256 + threadIdx.x;
    unsigned short* qh = (unsigned short*)ws;
    unsigned short* ql = qh + 49152;
    unsigned short* ph = (unsigned short*)((char*)ws + 196608);
    unsigned short* pl = (unsigned short*)((char*)ws + 229376);
    float* biasT = (float*)((char*)ws + WS_BIAS_OFF);
    if (i < 49152){
        float v = qkv_w[i];
        unsigned u = __float_as_uint(v);
        qh[i] = (unsigned short)(u >> 16);
        ql[i] = (unsigned short)(__float_as_uint(v - __uint_as_float(u & 0xffff0000u)) >> 16);
    } else if (i < 65536){
        int j = i - 49152;
        float v = proj_w[j];
        unsigned u = __float_as_uint(v);
        ph[j] = (unsigned short)(u >> 16);
        pl[j] = (unsigned short)(__float_as_uint(v - __uint_as_float(u & 0xffff0000u)) >> 16);
    } else if (i < 75140){
        int j = i - 65536;
        int h = j / 2401, r = j % 2401;       // r = q*49 + k
        biasT[h*2401 + r] = rel_table[rel_index[r]*4 + h];
    }
}

#define MFMA(a,b,c) __builtin_amdgcn_mfma_f32_16x16x32_bf16((a),(b),(c),0,0,0)

__global__ __launch_bounds__(256, 2)
void win_attn(const float* __restrict__ x, const float* __restrict__ u_temp,
              const float* __restrict__ u_bias, const float* __restrict__ gate,
              const float* __restrict__ qkv_b, const float* __restrict__ proj_b,
              const void* __restrict__ ws, float* __restrict__ out)
{
    __shared__ float sm[LDS_TOT];
    const int b = blockIdx.x, tid = threadIdx.x;
    const int l  = tid & 63;
    const int w  = __builtin_amdgcn_readfirstlane(tid >> 6);   // wave = head
    const int lc = l & 15, q4 = l >> 4;

    // ---- stage per-window scalars ----
    if (tid < NTOK){
        float u  = u_temp[b*NTOK + tid];
        float sg = 1.f / (1.f + __expf(-u));
        sm[LDS_RT + tid] = 0.17677669529663687f / (0.1f + 4.f*sg);   // (1/sqrt32)/T
        float ub = u_bias[b*NTOK + tid];
        sm[LDS_UB + tid] = ub > 0.f ? ub : 0.f;
    }
    if (tid < 196) sm[LDS_GATE + tid] = gate[b*196 + tid];
    __syncthreads();

    const unsigned short* qkh = (const unsigned short*)ws;
    const unsigned short* qkl = qkh + 49152;

    // ---- phase A: QKV GEMM (split-bf16, 3 MFMAs) ----
    f4v vhold[2][4];   // v D-tiles [t][mt] held in regs
    #pragma unroll
    for (int mp = 0; mp < 2; ++mp){
        s8v ah[2][4], al[2][4];
        #pragma unroll
        for (int m2 = 0; m2 < 2; ++m2){
            int row = (mp*2 + m2)*16 + lc; if (row > 48) row = 48;
            const float* xp = x + ((size_t)b*NTOK + row)*128 + q4*8;
            #pragma unroll
            for (int kf = 0; kf < 4; ++kf){
                float xv[8];
                float4 t0 = *(const float4*)(xp + kf*32);
                float4 t1 = *(const float4*)(xp + kf*32 + 4);
                xv[0]=t0.x; xv[1]=t0.y; xv[2]=t0.z; xv[3]=t0.w;
                xv[4]=t1.x; xv[5]=t1.y; xv[6]=t1.z; xv[7]=t1.w;
                split8t(xv, ah[m2][kf], al[m2][kf]);
            }
        }
        #pragma unroll
        for (int g = 0; g < 3; ++g){
            #pragma unroll
            for (int t = 0; t < 2; ++t){
                int nt  = (g==0 ? 2*w : (g==1 ? 8+2*w : 16+2*w)) + t;
                int col = nt*16 + lc;
                s8v bh[4], bl[4];
                #pragma unroll
                for (int kf = 0; kf < 4; ++kf){
                    int off = col*128 + kf*32 + q4*8;
                    bh[kf] = *(const s8v*)(qkh + off);
                    bl[kf] = *(const s8v*)(qkl + off);
                }
                float bia = qkv_b[col];
                #pragma unroll
                for (int m2 = 0; m2 < 2; ++m2){
                    f4v acc = {bia, bia, bia, bia};
                    #pragma unroll
                    for (int kf = 0; kf < 4; ++kf){
                        acc = MFMA(ah[m2][kf], bh[kf], acc);
                        acc = MFMA(ah[m2][kf], bl[kf], acc);
                        acc = MFMA(al[m2][kf], bh[kf], acc);
                    }
                    int mt = mp*2 + m2;
                    if (g == 2){
                        vhold[t][mt] = acc;
                    } else {
                        #pragma unroll
                        for (int r = 0; r < 4; ++r){
                            int row = mt*16 + q4*4 + r;
                            if (row < NTOK){
                                if (g == 0) sm[LDS_Q + row*132 + col] = acc[r] * sm[LDS_RT + row];
                                else        sm[LDS_K + row*132 + (col - 128)] = acc[r];
                            }
                        }
                    }
                }
            }
        }
    }
    __syncthreads();   // #2: q,k complete

    // ---- phase B: S^T = K·Q^T per head ----
    s8v Kh[4], Kl[4], Qh[4], Ql[4];
    #pragma unroll
    for (int t = 0; t < 4; ++t){
        int row = 16*t + lc; if (row > 48) row = 48;
        float fv[8];
        {
            const float* p = &sm[LDS_K + row*132 + w*32 + q4*8];
            float4 a0 = *(const float4*)p; float4 a1 = *(const float4*)(p + 4);
            fv[0]=a0.x; fv[1]=a0.y; fv[2]=a0.z; fv[3]=a0.w;
            fv[4]=a1.x; fv[5]=a1.y; fv[6]=a1.z; fv[7]=a1.w;
            split8t(fv, Kh[t], Kl[t]);
        }
        {
            const float* p = &sm[LDS_Q + row*132 + w*32 + q4*8];
            float4 a0 = *(const float4*)p; float4 a1 = *(const float4*)(p + 4);
            fv[0]=a0.x; fv[1]=a0.y; fv[2]=a0.z; fv[3]=a0.w;
            fv[4]=a1.x; fv[5]=a1.y; fv[6]=a1.z; fv[7]=a1.w;
            split8t(fv, Qh[t], Ql[t]);
        }
    }
    const float* biasT = (const float*)((const char*)ws + WS_BIAS_OFF);
    f4v S[4][4];   // S^T tiles: row=key, col=query
    #pragma unroll
    for (int mt = 0; mt < 4; ++mt){
        #pragma unroll
        for (int nt = 0; nt < 4; ++nt){
            int qy = nt*16 + lc; if (qy > 48) qy = 48;
            f4v a;
            #pragma unroll
            for (int r = 0; r < 4; ++r){
                int ky = mt*16 + q4*4 + r; if (ky > 48) ky = 48;
                a[r] = biasT[w*2401 + qy*49 + ky] - sm[LDS_UB + ky];
            }
            a = MFMA(Kh[mt], Qh[nt], a);
            a = MFMA(Kh[mt], Ql[nt], a);
            a = MFMA(Kl[mt], Qh[nt], a);
            S[mt][nt] = a;
        }
    }
    #pragma unroll
    for (int r = 0; r < 4; ++r){
        int ky = 48 + q4*4 + r;
        if (ky >= NTOK){
            S[3][0][r] = -1e30f; S[3][1][r] = -1e30f; S[3][2][r] = -1e30f; S[3][3][r] = -1e30f;
        }
    }
    #pragma unroll
    for (int nt = 0; nt < 4; ++nt){
        float mx = -3e38f;
        #pragma unroll
        for (int mt = 0; mt < 4; ++mt)
            #pragma unroll
            for (int r = 0; r < 4; ++r) mx = fmaxf(mx, S[mt][nt][r]);
        mx = fmaxf(mx, __shfl_xor(mx, 16));
        mx = fmaxf(mx, __shfl_xor(mx, 32));
        float sum = 0.f;
        #pragma unroll
        for (int mt = 0; mt < 4; ++mt)
            #pragma unroll
            for (int r = 0; r < 4; ++r){
                float e = __expf(S[mt][nt][r] - mx);
                S[mt][nt][r] = e; sum += e;
            }
        sum += __shfl_xor(sum, 16);
        sum += __shfl_xor(sum, 32);
        float rs = 1.f / sum;
        #pragma unroll
        for (int mt = 0; mt < 4; ++mt)
            #pragma unroll
            for (int r = 0; r < 4; ++r) S[mt][nt][r] *= rs;
    }
    __syncthreads();   // #3: all waves done reading q,k slots

    // ---- write P (bf16, q-slot, XOR-swizzled) and v (fp32, k-slot) ----
    unsigned short* P = (unsigned short*)sm;
    #pragma unroll
    for (int nt = 0; nt < 4; ++nt){
        int qy = nt*16 + lc;
        if (qy < NTOK){
            #pragma unroll
            for (int mt = 0; mt < 4; ++mt)
                #pragma unroll
                for (int r = 0; r < 4; ++r){
                    int ky = mt*16 + q4*4 + r;
                    P[w*3136 + qy*64 + (((ky>>3) ^ (qy&7)) << 3) + (ky&7)] = f2bf(S[mt][nt][r]);
                }
        }
    }
    #pragma unroll
    for (int t = 0; t < 2; ++t)
        #pragma unroll
        for (int mt = 0; mt < 4; ++mt)
            #pragma unroll
            for (int r = 0; r < 4; ++r){
                int row = mt*16 + q4*4 + r;
                if (row < NTOK) sm[LDS_K + row*132 + w*32 + t*16 + lc] = vhold[t][mt][r];
            }

    // ---- PV (same-wave LDS round trip) ----
    s8v Pa[4][2];
    #pragma unroll
    for (int mt = 0; mt < 4; ++mt)
        #pragma unroll
        for (int kf = 0; kf < 2; ++kf){
            int qy = mt*16 + lc; if (qy > 48) qy = 48;
            int ch = (4*kf + q4) ^ (qy & 7);
            Pa[mt][kf] = *(const s8v*)(P + w*3136 + qy*64 + ch*8);
        }
    s8v Vb[2][2];
    #pragma unroll
    for (int t = 0; t < 2; ++t)
        #pragma unroll
        for (int kf = 0; kf < 2; ++kf){
            #pragma unroll
            for (int j = 0; j < 8; ++j){
                int key = kf*32 + q4*8 + j; if (key > 48) key = 48;
                Vb[t][kf][j] = (short)(__float_as_uint(sm[LDS_K + key*132 + w*32 + t*16 + lc]) >> 16);
            }
        }
    f4v O[4][2];
    #pragma unroll
    for (int mt = 0; mt < 4; ++mt)
        #pragma unroll
        for (int t = 0; t < 2; ++t){
            f4v o = {0.f, 0.f, 0.f, 0.f};
            o = MFMA(Pa[mt][0], Vb[t][0], o);
            o = MFMA(Pa[mt][1], Vb[t][1], o);
            O[mt][t] = o;
        }
    __syncthreads();   // #4: all P/v reads done; q-slot reusable

    // ---- gate + stage attn_out pre-split (u16 hi/lo, chunk-XOR-swizzled, q-slot) ----
    unsigned short* ahh = (unsigned short*)sm;          // [49][16 chunks][8]
    unsigned short* all_ = ahh + 6272;
    #pragma unroll
    for (int mt = 0; mt < 4; ++mt)
        #pragma unroll
        for (int t = 0; t < 2; ++t)
            #pragma unroll
            for (int r = 0; r < 4; ++r){
                int row = mt*16 + q4*4 + r;
                if (row < NTOK){
                    int col = w*32 + t*16 + lc;
                    float v = O[mt][t][r] * sm[LDS_GATE + w*49 + row];
                    unsigned u = __float_as_uint(v);
                    float res = v - __uint_as_float(u & 0xffff0000u);
                    int idx = row*128 + (((col>>3) ^ (row&15)) << 3) + (col&7);
                    ahh[idx]  = (unsigned short)(u >> 16);
                    all_[idx] = (unsigned short)(__float_as_uint(res) >> 16);
                }
            }
    __syncthreads();   // #5: attn_out complete

    // ---- proj GEMM (split-bf16, 3 MFMAs); A-frags are pure b128 loads ----
    const unsigned short* ph = (const unsigned short*)((const char*)ws + 196608);
    const unsigned short* pl = (const unsigned short*)((const char*)ws + 229376);
    s8v Bh[2][4], Bl[2][4];
    #pragma unroll
    for (int t = 0; t < 2; ++t){
        int col = (2*w + t)*16 + lc;
        #pragma unroll
        for (int kf = 0; kf < 4; ++kf){
            int off = col*128 + kf*32 + q4*8;
            Bh[t][kf] = *(const s8v*)(ph + off);
            Bl[t][kf] = *(const s8v*)(pl + off);
        }
    }
    #pragma unroll
    for (int mt = 0; mt < 4; ++mt){
        int row = mt*16 + lc; if (row > 48) row = 48;
        s8v Ah[4], Al[4];
        #pragma unroll
        for (int kf = 0; kf < 4; ++kf){
            int phys = (4*kf + q4) ^ (row & 15);
            Ah[kf] = *(const s8v*)(ahh  + row*128 + phys*8);
            Al[kf] = *(const s8v*)(all_ + row*128 + phys*8);
        }
        #pragma unroll
        for (int t = 0; t < 2; ++t){
            int col = (2*w + t)*16 + lc;
            float bia = proj_b[col];
            f4v acc = {bia, bia, bia, bia};
            #pragma unroll
            for (int kf = 0; kf < 4; ++kf){
                acc = MFMA(Ah[kf], Bh[t][kf], acc);
                acc = MFMA(Ah[kf], Bl[t][kf], acc);
                acc = MFMA(Al[kf], Bh[t][kf], acc);
            }
            #pragma unroll
            for (int r = 0; r < 4; ++r){
                int r2 = mt*16 + q4*4 + r;
                if (r2 < NTOK) out[((size_t)b*NTOK + r2)*128 + col] = acc[r];
            }
        }
    }
}

extern "C" void kernel_launch(void* const* d_in, const int* in_sizes, int n_in,
                              void* d_out, int out_size, void* d_ws, size_t ws_size,
                              hipStream_t stream) {
    const float* x  = (const float*)d_in[0];
    const float* ut = (const float*)d_in[1];
    const float* ub = (const float*)d_in[2];
    const float* tg = (const float*)d_in[3];
    const float* qw = (const float*)d_in[4];
    const float* qb = (const float*)d_in[5];
    const float* pw = (const float*)d_in[6];
    const float* pb = (const float*)d_in[7];
    const float* rt = (const float*)d_in[8];
    const int*   ri = (const int*)d_in[9];
    float* o = (float*)d_out;
    const int B = in_sizes[0] / (NTOK * 128);

    prep_kernel<<<294, 256, 0, stream>>>(qw, pw, rt, ri, d_ws);
    win_attn<<<B, 256, 0, stream>>>(x, ut, ub, tg, qb, pb, d_ws, o);
}

// Round 4
// 449.108 us; speedup vs baseline: 7.4914x; 1.0191x over previous
//
#include <hip/hip_runtime.h>

typedef short s8v __attribute__((ext_vector_type(8)));
typedef float f4v __attribute__((ext_vector_type(4)));

#define NTOK 49
// LDS float offsets
#define LDS_Q    0        // fp32 [49][132] q (wave w owns cols 32w..32w+31); P[w] overlays same cols
#define LDS_K    6468     // fp32 [49][132] k (per-wave cols); v[w] then attn_hi/lo[w] overlay same cols
#define LDS_RT   12936    // [49] 0.17678/T
#define LDS_UB   12985    // [49] relu(u_bias)
#define LDS_GATE 13034    // [4][49]
#define LDS_TOT  13230    // 52920 bytes -> 53248 granule; 3 blocks/CU

// ws byte layout: qkv_hi u16[49152] @0 ; qkv_lo @98304 ; proj_hi u16[16384] @196608 ;
//                 proj_lo @229376 ; bias f32[4][49][49] @262144
#define WS_BIAS_OFF 262144

__device__ __forceinline__ unsigned short f2bf(float f){          // RNE
    unsigned x = __float_as_uint(f);
    x += 0x7fffu + ((x >> 16) & 1u);
    return (unsigned short)(x >> 16);
}
// truncation split: hi = top16(f), lo = top16(f - hi). err <= 2^-16 |f|
__device__ __forceinline__ void split8t(const float* f, s8v& hi, s8v& lo){
    #pragma unroll
    for (int j = 0; j < 8; ++j){
        unsigned u = __float_as_uint(f[j]);
        hi[j] = (short)(u >> 16);
        float r = f[j] - __uint_as_float(u & 0xffff0000u);
        lo[j] = (short)(__float_as_uint(r) >> 16);
    }
}

__global__ void prep_kernel(const float* __restrict__ qkv_w, const float* __restrict__ proj_w,
                            const float* __restrict__ rel_table, const int* __restrict__ rel_index,
                            void* __restrict__ ws){
    int i = blockIdx.x * 256 + threadIdx.x;
    unsigned short* qh = (unsigned short*)ws;
    unsigned short* ql = qh + 49152;
    unsigned short* ph = (unsigned short*)((char*)ws + 196608);
    unsigned short* pl = (unsigned short*)((char*)ws + 229376);
    float* biasT = (float*)((char*)ws + WS_BIAS_OFF);
    if (i < 49152){
        float v = qkv_w[i];
        unsigned u = __float_as_uint(v);
        qh[i] = (unsigned short)(u >> 16);
        ql[i] = (unsigned short)(__float_as_uint(v - __uint_as_float(u & 0xffff0000u)) >> 16);
    } else if (i < 65536){
        int j = i - 49152;
        float v = proj_w[j];
        unsigned u = __float_as_uint(v);
        ph[j] = (unsigned short)(u >> 16);
        pl[j] = (unsigned short)(__float_as_uint(v - __uint_as_float(u & 0xffff0000u)) >> 16);
    } else if (i < 75140){
        int j = i - 65536;
        int h = j / 2401, r = j % 2401;       // r = q*49 + k
        biasT[h*2401 + r] = rel_table[rel_index[r]*4 + h];
    }
}

#define MFMA(a,b,c) __builtin_amdgcn_mfma_f32_16x16x32_bf16((a),(b),(c),0,0,0)

__global__ __launch_bounds__(256, 2)
void win_attn(const float* __restrict__ x, const float* __restrict__ u_temp,
              const float* __restrict__ u_bias, const float* __restrict__ gate,
              const float* __restrict__ qkv_b, const float* __restrict__ proj_b,
              const void* __restrict__ ws, float* __restrict__ out)
{
    __shared__ float sm[LDS_TOT];
    const int b = blockIdx.x, tid = threadIdx.x;
    const int l  = tid & 63;
    const int w  = __builtin_amdgcn_readfirstlane(tid >> 6);   // wave = head
    const int lc = l & 15, q4 = l >> 4;

    // ---- stage per-window scalars ----
    if (tid < NTOK){
        float u  = u_temp[b*NTOK + tid];
        float sg = 1.f / (1.f + __expf(-u));
        sm[LDS_RT + tid] = 0.17677669529663687f / (0.1f + 4.f*sg);   // (1/sqrt32)/T
        float ub = u_bias[b*NTOK + tid];
        sm[LDS_UB + tid] = ub > 0.f ? ub : 0.f;
    }
    if (tid < 196) sm[LDS_GATE + tid] = gate[b*196 + tid];
    __syncthreads();   // #1: the only pre-proj barrier

    const unsigned short* qkh = (const unsigned short*)ws;
    const unsigned short* qkl = qkh + 49152;

    // ---- phase A: QKV GEMM (split-bf16, 3 MFMAs). Wave w computes head w's q,k,v only. ----
    f4v vhold[2][4];   // v D-tiles [t][mt] held in regs
    #pragma unroll
    for (int mp = 0; mp < 2; ++mp){
        s8v ah[2][4], al[2][4];
        #pragma unroll
        for (int m2 = 0; m2 < 2; ++m2){
            int row = (mp*2 + m2)*16 + lc; if (row > 48) row = 48;
            const float* xp = x + ((size_t)b*NTOK + row)*128 + q4*8;
            #pragma unroll
            for (int kf = 0; kf < 4; ++kf){
                float xv[8];
                float4 t0 = *(const float4*)(xp + kf*32);
                float4 t1 = *(const float4*)(xp + kf*32 + 4);
                xv[0]=t0.x; xv[1]=t0.y; xv[2]=t0.z; xv[3]=t0.w;
                xv[4]=t1.x; xv[5]=t1.y; xv[6]=t1.z; xv[7]=t1.w;
                split8t(xv, ah[m2][kf], al[m2][kf]);
            }
        }
        #pragma unroll
        for (int g = 0; g < 3; ++g){
            #pragma unroll
            for (int t = 0; t < 2; ++t){
                int nt  = (g==0 ? 2*w : (g==1 ? 8+2*w : 16+2*w)) + t;
                int col = nt*16 + lc;
                s8v bh[4], bl[4];
                #pragma unroll
                for (int kf = 0; kf < 4; ++kf){
                    int off = col*128 + kf*32 + q4*8;
                    bh[kf] = *(const s8v*)(qkh + off);
                    bl[kf] = *(const s8v*)(qkl + off);
                }
                float bia = qkv_b[col];
                #pragma unroll
                for (int m2 = 0; m2 < 2; ++m2){
                    f4v acc = {bia, bia, bia, bia};
                    #pragma unroll
                    for (int kf = 0; kf < 4; ++kf){
                        acc = MFMA(ah[m2][kf], bh[kf], acc);
                        acc = MFMA(ah[m2][kf], bl[kf], acc);
                        acc = MFMA(al[m2][kf], bh[kf], acc);
                    }
                    int mt = mp*2 + m2;
                    if (g == 2){
                        vhold[t][mt] = acc;
                    } else {
                        #pragma unroll
                        for (int r = 0; r < 4; ++r){
                            int row = mt*16 + q4*4 + r;
                            if (row < NTOK){
                                if (g == 0) sm[LDS_Q + row*132 + col] = acc[r] * sm[LDS_RT + row];
                                else        sm[LDS_K + row*132 + (col - 128)] = acc[r];
                            }
                        }
                    }
                }
            }
        }
    }
    // no barrier: wave w reads only its own q/k columns below

    // ---- phase B: S^T = K·Q^T per head ----
    s8v Kh[4], Kl[4], Qh[4], Ql[4];
    #pragma unroll
    for (int t = 0; t < 4; ++t){
        int row = 16*t + lc; if (row > 48) row = 48;
        float fv[8];
        {
            const float* p = &sm[LDS_K + row*132 + w*32 + q4*8];
            float4 a0 = *(const float4*)p; float4 a1 = *(const float4*)(p + 4);
            fv[0]=a0.x; fv[1]=a0.y; fv[2]=a0.z; fv[3]=a0.w;
            fv[4]=a1.x; fv[5]=a1.y; fv[6]=a1.z; fv[7]=a1.w;
            split8t(fv, Kh[t], Kl[t]);
        }
        {
            const float* p = &sm[LDS_Q + row*132 + w*32 + q4*8];
            float4 a0 = *(const float4*)p; float4 a1 = *(const float4*)(p + 4);
            fv[0]=a0.x; fv[1]=a0.y; fv[2]=a0.z; fv[3]=a0.w;
            fv[4]=a1.x; fv[5]=a1.y; fv[6]=a1.z; fv[7]=a1.w;
            split8t(fv, Qh[t], Ql[t]);
        }
    }
    const float* biasT = (const float*)((const char*)ws + WS_BIAS_OFF);
    f4v S[4][4];   // S^T tiles: row=key, col=query
    #pragma unroll
    for (int mt = 0; mt < 4; ++mt){
        #pragma unroll
        for (int nt = 0; nt < 4; ++nt){
            int qy = nt*16 + lc; if (qy > 48) qy = 48;
            f4v a;
            #pragma unroll
            for (int r = 0; r < 4; ++r){
                int ky = mt*16 + q4*4 + r; if (ky > 48) ky = 48;
                a[r] = biasT[w*2401 + qy*49 + ky] - sm[LDS_UB + ky];
            }
            a = MFMA(Kh[mt], Qh[nt], a);
            a = MFMA(Kh[mt], Ql[nt], a);
            a = MFMA(Kl[mt], Qh[nt], a);
            S[mt][nt] = a;
        }
    }
    #pragma unroll
    for (int r = 0; r < 4; ++r){
        int ky = 48 + q4*4 + r;
        if (ky >= NTOK){
            S[3][0][r] = -1e30f; S[3][1][r] = -1e30f; S[3][2][r] = -1e30f; S[3][3][r] = -1e30f;
        }
    }
    #pragma unroll
    for (int nt = 0; nt < 4; ++nt){
        float mx = -3e38f;
        #pragma unroll
        for (int mt = 0; mt < 4; ++mt)
            #pragma unroll
            for (int r = 0; r < 4; ++r) mx = fmaxf(mx, S[mt][nt][r]);
        mx = fmaxf(mx, __shfl_xor(mx, 16));
        mx = fmaxf(mx, __shfl_xor(mx, 32));
        float sum = 0.f;
        #pragma unroll
        for (int mt = 0; mt < 4; ++mt)
            #pragma unroll
            for (int r = 0; r < 4; ++r){
                float e = __expf(S[mt][nt][r] - mx);
                S[mt][nt][r] = e; sum += e;
            }
        sum += __shfl_xor(sum, 16);
        sum += __shfl_xor(sum, 32);
        float rs = 1.f / sum;
        #pragma unroll
        for (int mt = 0; mt < 4; ++mt)
            #pragma unroll
            for (int r = 0; r < 4; ++r) S[mt][nt][r] *= rs;
    }
    // no barrier: overlays below touch only wave w's own columns

    // ---- write P (bf16, q-slot cols 32w as u16 pairs, XOR-swizzled) and v (fp32, k-slot cols 32w) ----
    unsigned short* P = (unsigned short*)sm;
    #pragma unroll
    for (int nt = 0; nt < 4; ++nt){
        int qy = nt*16 + lc;
        if (qy < NTOK){
            #pragma unroll
            for (int mt = 0; mt < 4; ++mt)
                #pragma unroll
                for (int r = 0; r < 4; ++r){
                    int ky = mt*16 + q4*4 + r;
                    P[(qy*132 + w*32)*2 + (((ky>>3) ^ (qy&7)) << 3) + (ky&7)] = f2bf(S[mt][nt][r]);
                }
        }
    }
    #pragma unroll
    for (int t = 0; t < 2; ++t)
        #pragma unroll
        for (int mt = 0; mt < 4; ++mt)
            #pragma unroll
            for (int r = 0; r < 4; ++r){
                int row = mt*16 + q4*4 + r;
                if (row < NTOK) sm[LDS_K + row*132 + w*32 + t*16 + lc] = vhold[t][mt][r];
            }

    // ---- PV (same-wave LDS round trip) ----
    s8v Pa[4][2];
    #pragma unroll
    for (int mt = 0; mt < 4; ++mt)
        #pragma unroll
        for (int kf = 0; kf < 2; ++kf){
            int qy = mt*16 + lc; if (qy > 48) qy = 48;
            int ch = (4*kf + q4) ^ (qy & 7);
            Pa[mt][kf] = *(const s8v*)(P + (qy*132 + w*32)*2 + ch*8);
        }
    s8v Vb[2][2];
    #pragma unroll
    for (int t = 0; t < 2; ++t)
        #pragma unroll
        for (int kf = 0; kf < 2; ++kf){
            #pragma unroll
            for (int j = 0; j < 8; ++j){
                int key = kf*32 + q4*8 + j; if (key > 48) key = 48;
                Vb[t][kf][j] = (short)(__float_as_uint(sm[LDS_K + key*132 + w*32 + t*16 + lc]) >> 16);
            }
        }
    f4v O[4][2];
    #pragma unroll
    for (int mt = 0; mt < 4; ++mt)
        #pragma unroll
        for (int t = 0; t < 2; ++t){
            f4v o = {0.f, 0.f, 0.f, 0.f};
            o = MFMA(Pa[mt][0], Vb[t][0], o);
            o = MFMA(Pa[mt][1], Vb[t][1], o);
            O[mt][t] = o;
        }
    // no barrier: attn write below goes to wave w's own k-slot columns (own v, now dead)

    // ---- gate + stage attn_out pre-split: hi u16[0..31] then lo u16[0..31] per row, in k-cols 32w ----
    #pragma unroll
    for (int mt = 0; mt < 4; ++mt)
        #pragma unroll
        for (int t = 0; t < 2; ++t)
            #pragma unroll
            for (int r = 0; r < 4; ++r){
                int row = mt*16 + q4*4 + r;
                if (row < NTOK){
                    float vg = O[mt][t][r] * sm[LDS_GATE + w*49 + row];
                    unsigned u = __float_as_uint(vg);
                    float res = vg - __uint_as_float(u & 0xffff0000u);
                    char* bp = (char*)sm + (LDS_K + row*132 + w*32)*4;
                    ((unsigned short*)bp)[t*16 + lc]        = (unsigned short)(u >> 16);
                    ((unsigned short*)(bp + 64))[t*16 + lc] = (unsigned short)(__float_as_uint(res) >> 16);
                }
            }
    __syncthreads();   // #5: the single cross-wave handoff (all heads' attn_out -> proj)

    // ---- proj GEMM (split-bf16, 3 MFMAs); A-frags: head kf's block = k-cols 32*kf ----
    const unsigned short* ph = (const unsigned short*)((const char*)ws + 196608);
    const unsigned short* pl = (const unsigned short*)((const char*)ws + 229376);
    s8v Bh[2][4], Bl[2][4];
    #pragma unroll
    for (int t = 0; t < 2; ++t){
        int col = (2*w + t)*16 + lc;
        #pragma unroll
        for (int kf = 0; kf < 4; ++kf){
            int off = col*128 + kf*32 + q4*8;
            Bh[t][kf] = *(const s8v*)(ph + off);
            Bl[t][kf] = *(const s8v*)(pl + off);
        }
    }
    #pragma unroll
    for (int mt = 0; mt < 4; ++mt){
        int row = mt*16 + lc; if (row > 48) row = 48;
        s8v Ah[4], Al[4];
        #pragma unroll
        for (int kf = 0; kf < 4; ++kf){
            const char* bp = (const char*)sm + (LDS_K + row*132 + kf*32)*4;
            Ah[kf] = *(const s8v*)(bp + q4*16);
            Al[kf] = *(const s8v*)(bp + 64 + q4*16);
        }
        #pragma unroll
        for (int t = 0; t < 2; ++t){
            int col = (2*w + t)*16 + lc;
            float bia = proj_b[col];
            f4v acc = {bia, bia, bia, bia};
            #pragma unroll
            for (int kf = 0; kf < 4; ++kf){
                acc = MFMA(Ah[kf], Bh[t][kf], acc);
                acc = MFMA(Ah[kf], Bl[t][kf], acc);
                acc = MFMA(Al[kf], Bh[t][kf], acc);
            }
            #pragma unroll
            for (int r = 0; r < 4; ++r){
                int r2 = mt*16 + q4*4 + r;
                if (r2 < NTOK) out[((size_t)b*NTOK + r2)*128 + col] = acc[r];
            }
        }
    }
}

extern "C" void kernel_launch(void* const* d_in, const int* in_sizes, int n_in,
                              void* d_out, int out_size, void* d_ws, size_t ws_size,
                              hipStream_t stream) {
    const float* x  = (const float*)d_in[0];
    const float* ut = (const float*)d_in[1];
    const float* ub = (const float*)d_in[2];
    const float* tg = (const float*)d_in[3];
    const float* qw = (const float*)d_in[4];
    const float* qb = (const float*)d_in[5];
    const float* pw = (const float*)d_in[6];
    const float* pb = (const float*)d_in[7];
    const float* rt = (const float*)d_in[8];
    const int*   ri = (const int*)d_in[9];
    float* o = (float*)d_out;
    const int B = in_sizes[0] / (NTOK * 128);

    prep_kernel<<<294, 256, 0, stream>>>(qw, pw, rt, ri, d_ws);
    win_attn<<<B, 256, 0, stream>>>(x, ut, ub, tg, qb, pb, d_ws, o);
}